// Round 1
// baseline (1882.077 us; speedup 1.0000x reference)
//
#include <hip/hip_runtime.h>
#include <cstdint>

#define HDIM 128
#define EPSV 1e-5f

// ---- degree count: cnt[dst] += 1 ----
__global__ void k_count(const int* __restrict__ ei, float* __restrict__ cnt, int E) {
    int e = blockIdx.x * blockDim.x + threadIdx.x;
    if (e < E) atomicAdd(&cnt[ei[E + e]], 1.0f);
}

// ---- scatter-add feature rows: agg[dst] += feat[src]; one wave per edge ----
__global__ void k_scatter(const int* __restrict__ ei, const float* __restrict__ feat,
                          float* __restrict__ agg, int E) {
    int idx = blockIdx.x * blockDim.x + threadIdx.x;
    int wave = idx >> 6;
    int lane = idx & 63;
    if (wave >= E) return;
    int s = ei[wave];
    int d = ei[E + wave];
    float2 v = ((const float2*)(feat + (size_t)s * HDIM))[lane];
    float* a = agg + (size_t)d * HDIM + lane * 2;
    atomicAdd(a,     v.x);
    atomicAdd(a + 1, v.y);
}

// ---- fused SAGE linear, FOUT=128 ----
// out[i][j] = inv_i * (agg[i]·Wl[:,j]) + feat[i]·Wr[:,j] + bl[j]
// block=256, 16 rows per block staged in LDS; safe for out==feat (in-place).
__global__ __launch_bounds__(256) void k_gemm128(
    const float* __restrict__ feat, const float* __restrict__ agg,
    const float* __restrict__ cnt, const float* __restrict__ Wl,
    const float* __restrict__ bl, const float* __restrict__ Wr,
    float* __restrict__ out, int N) {
    __shared__ float a_s[16 * HDIM];
    __shared__ float x_s[16 * HDIM];
    int tid = threadIdx.x;
    int row0 = blockIdx.x * 16;

    const float4* af = (const float4*)(agg + (size_t)row0 * HDIM);
    const float4* xf = (const float4*)(feat + (size_t)row0 * HDIM);
    float4* as4 = (float4*)a_s;
    float4* xs4 = (float4*)x_s;
    #pragma unroll
    for (int t = tid; t < 512; t += 256) {
        if (row0 + (t >> 5) < N) { as4[t] = af[t]; xs4[t] = xf[t]; }
    }
    __syncthreads();

    int j = tid & 127;
    int slot = tid >> 7;           // 0..1
    float accl[8] = {0,0,0,0,0,0,0,0};
    float accr[8] = {0,0,0,0,0,0,0,0};

    for (int k = 0; k < HDIM; k += 4) {
        float wl0 = Wl[(k+0)*HDIM + j], wl1 = Wl[(k+1)*HDIM + j];
        float wl2 = Wl[(k+2)*HDIM + j], wl3 = Wl[(k+3)*HDIM + j];
        float wr0 = Wr[(k+0)*HDIM + j], wr1 = Wr[(k+1)*HDIM + j];
        float wr2 = Wr[(k+2)*HDIM + j], wr3 = Wr[(k+3)*HDIM + j];
        #pragma unroll
        for (int rr = 0; rr < 8; ++rr) {
            int r = slot + rr * 2;
            float4 av = *(const float4*)&a_s[r * HDIM + k];
            float4 xv = *(const float4*)&x_s[r * HDIM + k];
            accl[rr] += av.x*wl0 + av.y*wl1 + av.z*wl2 + av.w*wl3;
            accr[rr] += xv.x*wr0 + xv.y*wr1 + xv.z*wr2 + xv.w*wr3;
        }
    }
    float blj = bl[j];
    #pragma unroll
    for (int rr = 0; rr < 8; ++rr) {
        int row = row0 + slot + rr * 2;
        if (row < N) {
            float inv = 1.0f / fmaxf(cnt[row], 1.0f);
            out[(size_t)row * HDIM + j] = accl[rr] * inv + accr[rr] + blj;
        }
    }
}

// ---- fused SAGE linear, FOUT=C (47) ----
__global__ __launch_bounds__(256) void k_gemmC(
    const float* __restrict__ feat, const float* __restrict__ agg,
    const float* __restrict__ cnt, const float* __restrict__ Wl,
    const float* __restrict__ bl, const float* __restrict__ Wr,
    float* __restrict__ out, int N, int C) {
    __shared__ float a_s[16 * HDIM];
    __shared__ float x_s[16 * HDIM];
    int tid = threadIdx.x;
    int row0 = blockIdx.x * 16;

    const float4* af = (const float4*)(agg + (size_t)row0 * HDIM);
    const float4* xf = (const float4*)(feat + (size_t)row0 * HDIM);
    float4* as4 = (float4*)a_s;
    float4* xs4 = (float4*)x_s;
    #pragma unroll
    for (int t = tid; t < 512; t += 256) {
        if (row0 + (t >> 5) < N) { as4[t] = af[t]; xs4[t] = xf[t]; }
    }
    __syncthreads();

    int j = tid & 63;
    int slot = tid >> 6;           // 0..3
    if (j >= C) return;
    float accl[4] = {0,0,0,0};
    float accr[4] = {0,0,0,0};

    for (int k = 0; k < HDIM; ++k) {
        float wl = Wl[k * C + j];
        float wr = Wr[k * C + j];
        #pragma unroll
        for (int rr = 0; rr < 4; ++rr) {
            int r = slot + rr * 4;
            accl[rr] += a_s[r * HDIM + k] * wl;
            accr[rr] += x_s[r * HDIM + k] * wr;
        }
    }
    float bj = bl[j];
    #pragma unroll
    for (int rr = 0; rr < 4; ++rr) {
        int row = row0 + slot + rr * 4;
        if (row < N) {
            float inv = 1.0f / fmaxf(cnt[row], 1.0f);
            out[(size_t)row * C + j] = accl[rr] * inv + accr[rr] + bj;
        }
    }
}

// ---- BN stats: stats[j]=sum, stats[128+j]=sumsq (atomics) ----
__global__ void k_bnstats(const float* __restrict__ h, float* __restrict__ stats, int N) {
    int j = threadIdx.x & 127;
    int slot = threadIdx.x >> 7;   // 0..1
    float s1 = 0.f, s2 = 0.f;
    for (int r = blockIdx.x * 2 + slot; r < N; r += gridDim.x * 2) {
        float v = h[(size_t)r * HDIM + j];
        s1 += v;
        s2 += v * v;
    }
    atomicAdd(&stats[j], s1);
    atomicAdd(&stats[HDIM + j], s2);
}

// ---- BN apply + ReLU, in-place, float4 ----
__global__ void k_bnapply(float* __restrict__ h, const float* __restrict__ stats,
                          const float* __restrict__ g, const float* __restrict__ b, int N) {
    size_t i = (size_t)blockIdx.x * blockDim.x + threadIdx.x;
    size_t total = (size_t)N * (HDIM / 4);
    if (i >= total) return;
    float4 v = ((const float4*)h)[i];
    float* vp = (float*)&v;
    int jb = ((int)(i & 31)) * 4;
    float invN = 1.0f / (float)N;
    #pragma unroll
    for (int c = 0; c < 4; ++c) {
        int j = jb + c;
        float mu = stats[j] * invN;
        float var = stats[HDIM + j] * invN - mu * mu;
        float val = (vp[c] - mu) * rsqrtf(var + EPSV) * g[j] + b[j];
        vp[c] = fmaxf(val, 0.0f);
    }
    ((float4*)h)[i] = v;
}

// ---- log_softmax over C cols, one wave per row, in-place ----
__global__ void k_logsoftmax(float* __restrict__ out, int N, int C) {
    int idx = blockIdx.x * blockDim.x + threadIdx.x;
    int wave = idx >> 6;
    int lane = idx & 63;
    if (wave >= N) return;
    float v = (lane < C) ? out[(size_t)wave * C + lane] : -INFINITY;
    float m = v;
    #pragma unroll
    for (int o = 32; o; o >>= 1) m = fmaxf(m, __shfl_xor(m, o));
    float e = (lane < C) ? expf(v - m) : 0.0f;
    float s = e;
    #pragma unroll
    for (int o = 32; o; o >>= 1) s += __shfl_xor(s, o);
    if (lane < C) out[(size_t)wave * C + lane] = v - m - logf(s);
}

extern "C" void kernel_launch(void* const* d_in, const int* in_sizes, int n_in,
                              void* d_out, int out_size, void* d_ws, size_t ws_size,
                              hipStream_t stream) {
    const float* x   = (const float*)d_in[0];
    const int*   ei  = (const int*)d_in[1];
    const float* Wl0 = (const float*)d_in[2];
    const float* bl0 = (const float*)d_in[3];
    const float* Wr0 = (const float*)d_in[4];
    const float* g0  = (const float*)d_in[5];
    const float* b0  = (const float*)d_in[6];
    const float* Wl1 = (const float*)d_in[7];
    const float* bl1 = (const float*)d_in[8];
    const float* Wr1 = (const float*)d_in[9];
    const float* g1  = (const float*)d_in[10];
    const float* b1  = (const float*)d_in[11];
    const float* Wlo = (const float*)d_in[12];
    const float* blo = (const float*)d_in[13];
    const float* Wro = (const float*)d_in[14];

    int N = in_sizes[0] / HDIM;
    int E = in_sizes[1] / 2;
    int C = in_sizes[14] / HDIM;   // Wro is [128, C]
    float* out = (float*)d_out;

    float* cnt   = (float*)d_ws;                 // N
    float* agg   = cnt + N;                      // N*128
    float* h     = agg + (size_t)N * HDIM;       // N*128
    float* stats = h + (size_t)N * HDIM;         // 256

    // degree counts (once)
    hipMemsetAsync(cnt, 0, (size_t)N * sizeof(float), stream);
    k_count<<<(E + 255) / 256, 256, 0, stream>>>(ei, cnt, E);

    int scatter_blocks = (E + 3) / 4;            // 4 waves/block, 1 edge/wave
    int gemm_blocks = (N + 15) / 16;

    // ---- layer 0 ----
    hipMemsetAsync(agg, 0, (size_t)N * HDIM * sizeof(float), stream);
    k_scatter<<<scatter_blocks, 256, 0, stream>>>(ei, x, agg, E);
    k_gemm128<<<gemm_blocks, 256, 0, stream>>>(x, agg, cnt, Wl0, bl0, Wr0, h, N);
    hipMemsetAsync(stats, 0, 2 * HDIM * sizeof(float), stream);
    k_bnstats<<<256, 256, 0, stream>>>(h, stats, N);
    k_bnapply<<<(int)(((size_t)N * 32 + 255) / 256), 256, 0, stream>>>(h, stats, g0, b0, N);

    // ---- layer 1 (in-place on h) ----
    hipMemsetAsync(agg, 0, (size_t)N * HDIM * sizeof(float), stream);
    k_scatter<<<scatter_blocks, 256, 0, stream>>>(ei, h, agg, E);
    k_gemm128<<<gemm_blocks, 256, 0, stream>>>(h, agg, cnt, Wl1, bl1, Wr1, h, N);
    hipMemsetAsync(stats, 0, 2 * HDIM * sizeof(float), stream);
    k_bnstats<<<256, 256, 0, stream>>>(h, stats, N);
    k_bnapply<<<(int)(((size_t)N * 32 + 255) / 256), 256, 0, stream>>>(h, stats, g1, b1, N);

    // ---- output layer ----
    hipMemsetAsync(agg, 0, (size_t)N * HDIM * sizeof(float), stream);
    k_scatter<<<scatter_blocks, 256, 0, stream>>>(ei, h, agg, E);
    k_gemmC<<<gemm_blocks, 256, 0, stream>>>(h, agg, cnt, Wlo, blo, Wro, out, N, C);
    k_logsoftmax<<<(N * 64 + 255) / 256, 256, 0, stream>>>(out, N, C);
}

// Round 2
// 591.869 us; speedup vs baseline: 3.1799x; 3.1799x over previous
//
#include <hip/hip_runtime.h>
#include <cstdint>

#define HDIM 128
#define EPSV 1e-5f
#define SCAN_BLK 1024

// ---- int histogram of dst ----
__global__ void k_hist(const int* __restrict__ ei, int* __restrict__ cnt, int E) {
    int e = blockIdx.x * blockDim.x + threadIdx.x;
    if (e < E) atomicAdd(&cnt[ei[E + e]], 1);
}

// ---- scan phase 1: per-block (1024 elems) exclusive scan + block sums ----
__global__ __launch_bounds__(256) void k_scan1(const int* __restrict__ cnt,
                                               int* __restrict__ rowptr,
                                               int* __restrict__ bsum, int N) {
    __shared__ int lds[256];
    int b = blockIdx.x, t = threadIdx.x;
    int base = b * SCAN_BLK;
    int v[4]; int s = 0;
    #pragma unroll
    for (int c = 0; c < 4; ++c) { int i = base + t * 4 + c; v[c] = (i < N) ? cnt[i] : 0; s += v[c]; }
    lds[t] = s; __syncthreads();
    for (int off = 1; off < 256; off <<= 1) {
        int x = 0;
        if (t >= off) x = lds[t - off];
        __syncthreads();
        if (t >= off) lds[t] += x;
        __syncthreads();
    }
    int excl = (t > 0) ? lds[t - 1] : 0;
    if (t == 255) bsum[b] = lds[255];
    int run = excl;
    #pragma unroll
    for (int c = 0; c < 4; ++c) { int i = base + t * 4 + c; if (i < N) rowptr[i] = run; run += v[c]; }
}

// ---- scan phase 2: exclusive scan of block sums (nb <= 64, serial) ----
__global__ void k_scan2(int* __restrict__ bsum, int nb) {
    if (threadIdx.x == 0 && blockIdx.x == 0) {
        int run = 0;
        for (int i = 0; i < nb; ++i) { int v = bsum[i]; bsum[i] = run; run += v; }
    }
}

// ---- scan phase 3: add block offsets; set rowptr[N]=E ----
__global__ void k_scan3(int* __restrict__ rowptr, const int* __restrict__ bsum, int N, int E) {
    int i = blockIdx.x * blockDim.x + threadIdx.x;
    if (i < N) rowptr[i] += bsum[i / SCAN_BLK];
    if (i == 0) rowptr[N] = E;
}

// ---- CSR fill: col[rowptr[dst] + pos] = src ----
__global__ void k_fill(const int* __restrict__ ei, const int* __restrict__ rowptr,
                       int* __restrict__ fill, int* __restrict__ col, int E) {
    int e = blockIdx.x * blockDim.x + threadIdx.x;
    if (e < E) {
        int d = ei[E + e];
        int p = atomicAdd(&fill[d], 1);
        col[rowptr[d] + p] = ei[e];
    }
}

// ---- gather-aggregate with fused mean: agg[i] = mean_{s in N(i)} feat[s] ----
// one wave per node; lane holds float2 (128 floats / 64 lanes)
__global__ __launch_bounds__(256) void k_gather(const int* __restrict__ rowptr,
                                                const int* __restrict__ col,
                                                const float* __restrict__ feat,
                                                float* __restrict__ agg, int N) {
    int idx = blockIdx.x * blockDim.x + threadIdx.x;
    int wave = idx >> 6;
    int lane = idx & 63;
    if (wave >= N) return;
    int beg = rowptr[wave], end = rowptr[wave + 1];
    float ax = 0.f, ay = 0.f;
    int e = beg;
    for (; e + 1 < end; e += 2) {
        int s0 = col[e], s1 = col[e + 1];
        float2 v0 = ((const float2*)(feat + (size_t)s0 * HDIM))[lane];
        float2 v1 = ((const float2*)(feat + (size_t)s1 * HDIM))[lane];
        ax += v0.x + v1.x; ay += v0.y + v1.y;
    }
    if (e < end) {
        float2 v = ((const float2*)(feat + (size_t)col[e] * HDIM))[lane];
        ax += v.x; ay += v.y;
    }
    float inv = (end > beg) ? 1.0f / (float)(end - beg) : 0.0f;
    ((float2*)(agg + (size_t)wave * HDIM))[lane] = make_float2(ax * inv, ay * inv);
}

// ---- fused SAGE linear, FOUT=128: out = agg@Wl + feat@Wr + bl ----
__global__ __launch_bounds__(256) void k_gemm128(
    const float* __restrict__ feat, const float* __restrict__ agg,
    const float* __restrict__ Wl, const float* __restrict__ bl,
    const float* __restrict__ Wr, float* __restrict__ out, int N) {
    __shared__ float a_s[16 * HDIM];
    __shared__ float x_s[16 * HDIM];
    int tid = threadIdx.x;
    int row0 = blockIdx.x * 16;

    const float4* af = (const float4*)(agg + (size_t)row0 * HDIM);
    const float4* xf = (const float4*)(feat + (size_t)row0 * HDIM);
    float4* as4 = (float4*)a_s;
    float4* xs4 = (float4*)x_s;
    #pragma unroll
    for (int t = tid; t < 512; t += 256) {
        if (row0 + (t >> 5) < N) { as4[t] = af[t]; xs4[t] = xf[t]; }
    }
    __syncthreads();

    int j = tid & 127;
    int slot = tid >> 7;           // 0..1
    float accl[8] = {0,0,0,0,0,0,0,0};
    float accr[8] = {0,0,0,0,0,0,0,0};

    for (int k = 0; k < HDIM; k += 4) {
        float wl0 = Wl[(k+0)*HDIM + j], wl1 = Wl[(k+1)*HDIM + j];
        float wl2 = Wl[(k+2)*HDIM + j], wl3 = Wl[(k+3)*HDIM + j];
        float wr0 = Wr[(k+0)*HDIM + j], wr1 = Wr[(k+1)*HDIM + j];
        float wr2 = Wr[(k+2)*HDIM + j], wr3 = Wr[(k+3)*HDIM + j];
        #pragma unroll
        for (int rr = 0; rr < 8; ++rr) {
            int r = slot + rr * 2;
            float4 av = *(const float4*)&a_s[r * HDIM + k];
            float4 xv = *(const float4*)&x_s[r * HDIM + k];
            accl[rr] += av.x*wl0 + av.y*wl1 + av.z*wl2 + av.w*wl3;
            accr[rr] += xv.x*wr0 + xv.y*wr1 + xv.z*wr2 + xv.w*wr3;
        }
    }
    float blj = bl[j];
    #pragma unroll
    for (int rr = 0; rr < 8; ++rr) {
        int row = row0 + slot + rr * 2;
        if (row < N) out[(size_t)row * HDIM + j] = accl[rr] + accr[rr] + blj;
    }
}

// ---- fused SAGE linear, FOUT=C (47) ----
__global__ __launch_bounds__(256) void k_gemmC(
    const float* __restrict__ feat, const float* __restrict__ agg,
    const float* __restrict__ Wl, const float* __restrict__ bl,
    const float* __restrict__ Wr, float* __restrict__ out, int N, int C) {
    __shared__ float a_s[16 * HDIM];
    __shared__ float x_s[16 * HDIM];
    int tid = threadIdx.x;
    int row0 = blockIdx.x * 16;

    const float4* af = (const float4*)(agg + (size_t)row0 * HDIM);
    const float4* xf = (const float4*)(feat + (size_t)row0 * HDIM);
    float4* as4 = (float4*)a_s;
    float4* xs4 = (float4*)x_s;
    #pragma unroll
    for (int t = tid; t < 512; t += 256) {
        if (row0 + (t >> 5) < N) { as4[t] = af[t]; xs4[t] = xf[t]; }
    }
    __syncthreads();

    int j = tid & 63;
    int slot = tid >> 6;           // 0..3
    if (j >= C) return;
    float accl[4] = {0,0,0,0};
    float accr[4] = {0,0,0,0};

    for (int k = 0; k < HDIM; ++k) {
        float wl = Wl[k * C + j];
        float wr = Wr[k * C + j];
        #pragma unroll
        for (int rr = 0; rr < 4; ++rr) {
            int r = slot + rr * 4;
            accl[rr] += a_s[r * HDIM + k] * wl;
            accr[rr] += x_s[r * HDIM + k] * wr;
        }
    }
    float bj = bl[j];
    #pragma unroll
    for (int rr = 0; rr < 4; ++rr) {
        int row = row0 + slot + rr * 4;
        if (row < N) out[(size_t)row * C + j] = accl[rr] + accr[rr] + bj;
    }
}

// ---- BN stats: stats[j]=sum, stats[128+j]=sumsq (atomics) ----
__global__ void k_bnstats(const float* __restrict__ h, float* __restrict__ stats, int N) {
    int j = threadIdx.x & 127;
    int slot = threadIdx.x >> 7;   // 0..1
    float s1 = 0.f, s2 = 0.f;
    for (int r = blockIdx.x * 2 + slot; r < N; r += gridDim.x * 2) {
        float v = h[(size_t)r * HDIM + j];
        s1 += v;
        s2 += v * v;
    }
    atomicAdd(&stats[j], s1);
    atomicAdd(&stats[HDIM + j], s2);
}

// ---- BN apply + ReLU, in-place, float4 ----
__global__ void k_bnapply(float* __restrict__ h, const float* __restrict__ stats,
                          const float* __restrict__ g, const float* __restrict__ b, int N) {
    size_t i = (size_t)blockIdx.x * blockDim.x + threadIdx.x;
    size_t total = (size_t)N * (HDIM / 4);
    if (i >= total) return;
    float4 v = ((const float4*)h)[i];
    float* vp = (float*)&v;
    int jb = ((int)(i & 31)) * 4;
    float invN = 1.0f / (float)N;
    #pragma unroll
    for (int c = 0; c < 4; ++c) {
        int j = jb + c;
        float mu = stats[j] * invN;
        float var = stats[HDIM + j] * invN - mu * mu;
        float val = (vp[c] - mu) * rsqrtf(var + EPSV) * g[j] + b[j];
        vp[c] = fmaxf(val, 0.0f);
    }
    ((float4*)h)[i] = v;
}

// ---- log_softmax over C cols, one wave per row, in-place ----
__global__ void k_logsoftmax(float* __restrict__ out, int N, int C) {
    int idx = blockIdx.x * blockDim.x + threadIdx.x;
    int wave = idx >> 6;
    int lane = idx & 63;
    if (wave >= N) return;
    float v = (lane < C) ? out[(size_t)wave * C + lane] : -INFINITY;
    float m = v;
    #pragma unroll
    for (int o = 32; o; o >>= 1) m = fmaxf(m, __shfl_xor(m, o));
    float e = (lane < C) ? expf(v - m) : 0.0f;
    float s = e;
    #pragma unroll
    for (int o = 32; o; o >>= 1) s += __shfl_xor(s, o);
    if (lane < C) out[(size_t)wave * C + lane] = v - m - logf(s);
}

extern "C" void kernel_launch(void* const* d_in, const int* in_sizes, int n_in,
                              void* d_out, int out_size, void* d_ws, size_t ws_size,
                              hipStream_t stream) {
    const float* x   = (const float*)d_in[0];
    const int*   ei  = (const int*)d_in[1];
    const float* Wl0 = (const float*)d_in[2];
    const float* bl0 = (const float*)d_in[3];
    const float* Wr0 = (const float*)d_in[4];
    const float* g0  = (const float*)d_in[5];
    const float* b0  = (const float*)d_in[6];
    const float* Wl1 = (const float*)d_in[7];
    const float* bl1 = (const float*)d_in[8];
    const float* Wr1 = (const float*)d_in[9];
    const float* g1  = (const float*)d_in[10];
    const float* b1  = (const float*)d_in[11];
    const float* Wlo = (const float*)d_in[12];
    const float* blo = (const float*)d_in[13];
    const float* Wro = (const float*)d_in[14];

    int N = in_sizes[0] / HDIM;
    int E = in_sizes[1] / 2;
    int C = in_sizes[14] / HDIM;   // Wro is [128, C]
    float* out = (float*)d_out;

    // ---- workspace layout (ints first, 16B-aligned throughout) ----
    int*   col    = (int*)d_ws;                        // E
    int*   cnt    = col + E;                           // N
    int*   rowptr = cnt + N;                           // N+4 (padded)
    int*   fill   = rowptr + (N + 4);                  // N
    int*   bsum   = fill + N;                          // 64
    float* agg    = (float*)(bsum + 64);               // N*128
    float* h      = agg + (size_t)N * HDIM;            // N*128
    float* stats  = h + (size_t)N * HDIM;              // 256

    int nb = (N + SCAN_BLK - 1) / SCAN_BLK;

    // ---- CSR build ----
    hipMemsetAsync(cnt, 0, (size_t)N * sizeof(int), stream);
    hipMemsetAsync(fill, 0, (size_t)N * sizeof(int), stream);
    k_hist<<<(E + 255) / 256, 256, 0, stream>>>(ei, cnt, E);
    k_scan1<<<nb, 256, 0, stream>>>(cnt, rowptr, bsum, N);
    k_scan2<<<1, 64, 0, stream>>>(bsum, nb);
    k_scan3<<<(N + 255) / 256, 256, 0, stream>>>(rowptr, bsum, N, E);
    k_fill<<<(E + 255) / 256, 256, 0, stream>>>(ei, rowptr, fill, col, E);

    int gather_blocks = (N + 3) / 4;     // 4 waves/block, 1 node/wave
    int gemm_blocks = (N + 15) / 16;

    // ---- layer 0 ----
    k_gather<<<gather_blocks, 256, 0, stream>>>(rowptr, col, x, agg, N);
    k_gemm128<<<gemm_blocks, 256, 0, stream>>>(x, agg, Wl0, bl0, Wr0, h, N);
    hipMemsetAsync(stats, 0, 2 * HDIM * sizeof(float), stream);
    k_bnstats<<<256, 256, 0, stream>>>(h, stats, N);
    k_bnapply<<<(int)(((size_t)N * 32 + 255) / 256), 256, 0, stream>>>(h, stats, g0, b0, N);

    // ---- layer 1 (in-place on h) ----
    k_gather<<<gather_blocks, 256, 0, stream>>>(rowptr, col, h, agg, N);
    k_gemm128<<<gemm_blocks, 256, 0, stream>>>(h, agg, Wl1, bl1, Wr1, h, N);
    hipMemsetAsync(stats, 0, 2 * HDIM * sizeof(float), stream);
    k_bnstats<<<256, 256, 0, stream>>>(h, stats, N);
    k_bnapply<<<(int)(((size_t)N * 32 + 255) / 256), 256, 0, stream>>>(h, stats, g1, b1, N);

    // ---- output layer ----
    k_gather<<<gather_blocks, 256, 0, stream>>>(rowptr, col, h, agg, N);
    k_gemmC<<<gemm_blocks, 256, 0, stream>>>(h, agg, Wlo, blo, Wro, out, N, C);
    k_logsoftmax<<<(N * 64 + 255) / 256, 256, 0, stream>>>(out, N, C);
}

// Round 3
// 423.054 us; speedup vs baseline: 4.4488x; 1.3990x over previous
//
#include <hip/hip_runtime.h>
#include <cstdint>

#define HDIM 128
#define EPSV 1e-5f
#define SCAN_BLK 1024

typedef short  short8 __attribute__((ext_vector_type(8)));
typedef __bf16 bf16x8 __attribute__((ext_vector_type(8)));
typedef float  f32x4  __attribute__((ext_vector_type(4)));

__device__ __forceinline__ unsigned short f2bf_rne(float x) {
    unsigned int u = __float_as_uint(x);
    return (unsigned short)((u + 0x7FFFu + ((u >> 16) & 1u)) >> 16);
}

// ================= CSR build =================
__global__ void k_hist(const int* __restrict__ ei, int* __restrict__ cnt, int E) {
    int e = blockIdx.x * blockDim.x + threadIdx.x;
    if (e < E) atomicAdd(&cnt[ei[E + e]], 1);
}

__global__ __launch_bounds__(256) void k_scan1(const int* __restrict__ cnt,
                                               int* __restrict__ rowptr,
                                               int* __restrict__ bsum, int N) {
    __shared__ int lds[256];
    int b = blockIdx.x, t = threadIdx.x;
    int base = b * SCAN_BLK;
    int v[4]; int s = 0;
    #pragma unroll
    for (int c = 0; c < 4; ++c) { int i = base + t * 4 + c; v[c] = (i < N) ? cnt[i] : 0; s += v[c]; }
    lds[t] = s; __syncthreads();
    for (int off = 1; off < 256; off <<= 1) {
        int x = 0;
        if (t >= off) x = lds[t - off];
        __syncthreads();
        if (t >= off) lds[t] += x;
        __syncthreads();
    }
    int excl = (t > 0) ? lds[t - 1] : 0;
    if (t == 255) bsum[b] = lds[255];
    int run = excl;
    #pragma unroll
    for (int c = 0; c < 4; ++c) { int i = base + t * 4 + c; if (i < N) rowptr[i] = run; run += v[c]; }
}

__global__ void k_scan2(int* __restrict__ bsum, int nb) {
    if (threadIdx.x == 0 && blockIdx.x == 0) {
        int run = 0;
        for (int i = 0; i < nb; ++i) { int v = bsum[i]; bsum[i] = run; run += v; }
    }
}

__global__ void k_scan3(int* __restrict__ rowptr, const int* __restrict__ bsum, int N, int E) {
    int i = blockIdx.x * blockDim.x + threadIdx.x;
    if (i < N) rowptr[i] += bsum[i / SCAN_BLK];
    if (i == 0) rowptr[N] = E;
}

__global__ void k_fill(const int* __restrict__ ei, const int* __restrict__ rowptr,
                       int* __restrict__ fill, int* __restrict__ col, int E) {
    int e = blockIdx.x * blockDim.x + threadIdx.x;
    if (e < E) {
        int d = ei[E + e];
        int p = atomicAdd(&fill[d], 1);
        col[rowptr[d] + p] = ei[e];
    }
}

// ================= gather mean-aggregate =================
__global__ __launch_bounds__(256) void k_gather(const int* __restrict__ rowptr,
                                                const int* __restrict__ col,
                                                const float* __restrict__ feat,
                                                float* __restrict__ agg, int N) {
    int idx = blockIdx.x * blockDim.x + threadIdx.x;
    int wave = idx >> 6;
    int lane = idx & 63;
    if (wave >= N) return;
    int beg = rowptr[wave], end = rowptr[wave + 1];
    float ax = 0.f, ay = 0.f;
    int e = beg;
    for (; e + 1 < end; e += 2) {
        int s0 = col[e], s1 = col[e + 1];
        float2 v0 = ((const float2*)(feat + (size_t)s0 * HDIM))[lane];
        float2 v1 = ((const float2*)(feat + (size_t)s1 * HDIM))[lane];
        ax += v0.x + v1.x; ay += v0.y + v1.y;
    }
    if (e < end) {
        float2 v = ((const float2*)(feat + (size_t)col[e] * HDIM))[lane];
        ax += v.x; ay += v.y;
    }
    float inv = (end > beg) ? 1.0f / (float)(end - beg) : 0.0f;
    ((float2*)(agg + (size_t)wave * HDIM))[lane] = make_float2(ax * inv, ay * inv);
}

// ================= W pre-pack into MFMA B-fragment order =================
// B frag for 16x16x32: col = lane&15, k = (lane>>4)*8 + e.
// Packed linear index: ((ct*4 + kk)*64 + lane)*8 + e, per (mat,split) array of NT*2048.
__global__ void k_pack_all(const float* __restrict__ Wl0, const float* __restrict__ Wr0,
                           const float* __restrict__ Wl1, const float* __restrict__ Wr1,
                           const float* __restrict__ Wlo, const float* __restrict__ Wro,
                           unsigned short* __restrict__ pk0, unsigned short* __restrict__ pk1,
                           unsigned short* __restrict__ pko, int C) {
    const float* W; unsigned short* WH; unsigned short* WL; int FOUT, NT;
    switch (blockIdx.y) {
        case 0:  W = Wl0; WH = pk0;          WL = pk0 + 16384; FOUT = 128; NT = 8; break;
        case 1:  W = Wr0; WH = pk0 + 32768;  WL = pk0 + 49152; FOUT = 128; NT = 8; break;
        case 2:  W = Wl1; WH = pk1;          WL = pk1 + 16384; FOUT = 128; NT = 8; break;
        case 3:  W = Wr1; WH = pk1 + 32768;  WL = pk1 + 49152; FOUT = 128; NT = 8; break;
        case 4:  W = Wlo; WH = pko;          WL = pko + 6144;  FOUT = C;   NT = 3; break;
        default: W = Wro; WH = pko + 12288;  WL = pko + 18432; FOUT = C;   NT = 3; break;
    }
    int tid = blockIdx.x * 256 + threadIdx.x;
    if (tid >= NT * 2048) return;
    int e = tid & 7, lane = (tid >> 3) & 63, kk = (tid >> 9) & 3, ct = tid >> 11;
    int j = ct * 16 + (lane & 15);
    int k = kk * 32 + (lane >> 4) * 8 + e;
    float v = (j < FOUT) ? W[k * FOUT + j] : 0.0f;
    unsigned short h = f2bf_rne(v);
    float hf = __uint_as_float((unsigned int)h << 16);
    unsigned short l = f2bf_rne(v - hf);
    WH[tid] = h; WL[tid] = l;
}

// ================= fused SAGE linear via split-bf16 MFMA =================
// out[i][j] = agg[i]·Wl[:,j] + feat[i]·Wr[:,j] + bias[j]
// 32 rows/block, 4 waves; wave w covers column-tiles {w, w+4, ...} < NT.
// A staged in LDS as bf16 hi/lo, 16B slots XOR-swizzled: slot' = slot ^ (row&15).
// x·w = hi·hi + hi·lo + lo·hi  (3 MFMAs, ~fp32 precision).
template<int NT>
__global__ __launch_bounds__(256) void k_sage_mfma(
    const float* __restrict__ feat, const float* __restrict__ agg,
    const unsigned short* __restrict__ pk, const float* __restrict__ bias,
    float* __restrict__ out, int N, int FOUT) {
    __shared__ __align__(16) char smem[32768];   // [mat][split][32 rows][16 slots * 16B]
    int tid = threadIdx.x;
    int row0 = blockIdx.x * 32;

    // ---- stage A-tiles (mat 0 = agg/Wl, mat 1 = feat/Wr) ----
    #pragma unroll
    for (int mat = 0; mat < 2; ++mat) {
        const float* src = (mat == 0 ? agg : feat) + (size_t)row0 * HDIM;
        #pragma unroll
        for (int uu = 0; uu < 2; ++uu) {
            int u = tid + uu * 256;            // 0..511
            int row = u >> 4, slot = u & 15;
            float4 v0 = make_float4(0.f, 0.f, 0.f, 0.f);
            float4 v1 = make_float4(0.f, 0.f, 0.f, 0.f);
            if (row0 + row < N) {
                v0 = *(const float4*)(src + row * HDIM + slot * 8);
                v1 = *(const float4*)(src + row * HDIM + slot * 8 + 4);
            }
            float vv[8] = {v0.x, v0.y, v0.z, v0.w, v1.x, v1.y, v1.z, v1.w};
            short8 hi, lo;
            #pragma unroll
            for (int e = 0; e < 8; ++e) {
                unsigned short h = f2bf_rne(vv[e]);
                float hf = __uint_as_float((unsigned int)h << 16);
                unsigned short l = f2bf_rne(vv[e] - hf);
                hi[e] = (short)h; lo[e] = (short)l;
            }
            int sp = slot ^ (row & 15);
            *(short8*)(smem + ((mat * 2 + 0) * 32 + row) * 256 + sp * 16) = hi;
            *(short8*)(smem + ((mat * 2 + 1) * 32 + row) * 256 + sp * 16) = lo;
        }
    }
    __syncthreads();

    int w = tid >> 6, lane = tid & 63;
    int lr = lane & 15, lk = lane >> 4;
    f32x4 acc[2][2] = {};   // [rowtile][ct-slot]

    for (int kk = 0; kk < 4; ++kk) {
        // A fragments: row = rt*16 + lr, k = kk*32 + lk*8 .. +7
        bf16x8 a[2][2][2];   // [rt][mat][split]
        int sp = (kk * 4 + lk) ^ lr;
        #pragma unroll
        for (int rt = 0; rt < 2; ++rt)
            #pragma unroll
            for (int mat = 0; mat < 2; ++mat)
                #pragma unroll
                for (int s = 0; s < 2; ++s)
                    a[rt][mat][s] = *(const bf16x8*)(smem + ((mat * 2 + s) * 32 + rt * 16 + lr) * 256 + sp * 16);

        int ci = 0;
        #pragma unroll
        for (int ct0 = 0; ct0 < NT; ct0 += 4, ++ci) {
            int ct = ct0 + w;
            if (ct < NT) {
                int fo = ((ct * 4 + kk) * 64 + lane) * 8;
                #pragma unroll
                for (int mat = 0; mat < 2; ++mat) {
                    bf16x8 bH = *(const bf16x8*)(pk + (size_t)(mat * 2 + 0) * NT * 2048 + fo);
                    bf16x8 bL = *(const bf16x8*)(pk + (size_t)(mat * 2 + 1) * NT * 2048 + fo);
                    #pragma unroll
                    for (int rt = 0; rt < 2; ++rt) {
                        acc[rt][ci] = __builtin_amdgcn_mfma_f32_16x16x32_bf16(a[rt][mat][0], bH, acc[rt][ci], 0, 0, 0);
                        acc[rt][ci] = __builtin_amdgcn_mfma_f32_16x16x32_bf16(a[rt][mat][0], bL, acc[rt][ci], 0, 0, 0);
                        acc[rt][ci] = __builtin_amdgcn_mfma_f32_16x16x32_bf16(a[rt][mat][1], bH, acc[rt][ci], 0, 0, 0);
                    }
                }
            }
        }
    }

    // ---- epilogue: C/D layout col = lane&15, row = (lane>>4)*4 + reg ----
    int ci = 0;
    #pragma unroll
    for (int ct0 = 0; ct0 < NT; ct0 += 4, ++ci) {
        int ct = ct0 + w;
        if (ct < NT) {
            int colj = ct * 16 + lr;
            float bv = (colj < FOUT) ? bias[colj] : 0.f;
            #pragma unroll
            for (int rt = 0; rt < 2; ++rt) {
                #pragma unroll
                for (int r = 0; r < 4; ++r) {
                    int row = row0 + rt * 16 + lk * 4 + r;
                    if (row < N && colj < FOUT)
                        out[(size_t)row * FOUT + colj] = acc[rt][ci][r] + bv;
                }
            }
        }
    }
}

// ================= BatchNorm =================
__global__ void k_bnstats(const float* __restrict__ h, float* __restrict__ stats, int N) {
    int j = threadIdx.x & 127;
    int slot = threadIdx.x >> 7;
    float s1 = 0.f, s2 = 0.f;
    for (int r = blockIdx.x * 2 + slot; r < N; r += gridDim.x * 2) {
        float v = h[(size_t)r * HDIM + j];
        s1 += v;
        s2 += v * v;
    }
    atomicAdd(&stats[j], s1);
    atomicAdd(&stats[HDIM + j], s2);
}

__global__ void k_bnapply(float* __restrict__ h, const float* __restrict__ stats,
                          const float* __restrict__ g, const float* __restrict__ b, int N) {
    size_t i = (size_t)blockIdx.x * blockDim.x + threadIdx.x;
    size_t total = (size_t)N * (HDIM / 4);
    if (i >= total) return;
    float4 v = ((const float4*)h)[i];
    float* vp = (float*)&v;
    int jb = ((int)(i & 31)) * 4;
    float invN = 1.0f / (float)N;
    #pragma unroll
    for (int c = 0; c < 4; ++c) {
        int j = jb + c;
        float mu = stats[j] * invN;
        float var = stats[HDIM + j] * invN - mu * mu;
        float val = (vp[c] - mu) * rsqrtf(var + EPSV) * g[j] + b[j];
        vp[c] = fmaxf(val, 0.0f);
    }
    ((float4*)h)[i] = v;
}

// ================= log_softmax =================
__global__ void k_logsoftmax(float* __restrict__ out, int N, int C) {
    int idx = blockIdx.x * blockDim.x + threadIdx.x;
    int wave = idx >> 6;
    int lane = idx & 63;
    if (wave >= N) return;
    float v = (lane < C) ? out[(size_t)wave * C + lane] : -INFINITY;
    float m = v;
    #pragma unroll
    for (int o = 32; o; o >>= 1) m = fmaxf(m, __shfl_xor(m, o));
    float e = (lane < C) ? expf(v - m) : 0.0f;
    float s = e;
    #pragma unroll
    for (int o = 32; o; o >>= 1) s += __shfl_xor(s, o);
    if (lane < C) out[(size_t)wave * C + lane] = v - m - logf(s);
}

extern "C" void kernel_launch(void* const* d_in, const int* in_sizes, int n_in,
                              void* d_out, int out_size, void* d_ws, size_t ws_size,
                              hipStream_t stream) {
    const float* x   = (const float*)d_in[0];
    const int*   ei  = (const int*)d_in[1];
    const float* Wl0 = (const float*)d_in[2];
    const float* bl0 = (const float*)d_in[3];
    const float* Wr0 = (const float*)d_in[4];
    const float* g0  = (const float*)d_in[5];
    const float* b0  = (const float*)d_in[6];
    const float* Wl1 = (const float*)d_in[7];
    const float* bl1 = (const float*)d_in[8];
    const float* Wr1 = (const float*)d_in[9];
    const float* g1  = (const float*)d_in[10];
    const float* b1  = (const float*)d_in[11];
    const float* Wlo = (const float*)d_in[12];
    const float* blo = (const float*)d_in[13];
    const float* Wro = (const float*)d_in[14];

    int N = in_sizes[0] / HDIM;
    int E = in_sizes[1] / 2;
    int C = in_sizes[14] / HDIM;   // Wro is [128, C]
    float* out = (float*)d_out;

    // ---- workspace layout (16B-aligned blocks) ----
    int*   col    = (int*)d_ws;                        // E
    int*   cnt    = col + E;                           // N
    int*   rowptr = cnt + N;                           // N+4
    int*   fill   = rowptr + (N + 4);                  // N
    int*   bsum   = fill + N;                          // 64
    float* agg    = (float*)(bsum + 64);               // N*128
    float* h      = agg + (size_t)N * HDIM;            // N*128
    float* stats  = h + (size_t)N * HDIM;              // 256
    unsigned short* pk0 = (unsigned short*)(stats + 256);  // 65536
    unsigned short* pk1 = pk0 + 65536;                     // 65536
    unsigned short* pko = pk1 + 65536;                     // 24576

    int nb = (N + SCAN_BLK - 1) / SCAN_BLK;

    // ---- CSR build + weight pack (independent) ----
    hipMemsetAsync(cnt, 0, (size_t)N * sizeof(int), stream);
    hipMemsetAsync(fill, 0, (size_t)N * sizeof(int), stream);
    k_hist<<<(E + 255) / 256, 256, 0, stream>>>(ei, cnt, E);
    k_scan1<<<nb, 256, 0, stream>>>(cnt, rowptr, bsum, N);
    k_scan2<<<1, 64, 0, stream>>>(bsum, nb);
    k_scan3<<<(N + 255) / 256, 256, 0, stream>>>(rowptr, bsum, N, E);
    k_fill<<<(E + 255) / 256, 256, 0, stream>>>(ei, rowptr, fill, col, E);
    k_pack_all<<<dim3(64, 6), 256, 0, stream>>>(Wl0, Wr0, Wl1, Wr1, Wlo, Wro, pk0, pk1, pko, C);

    int gather_blocks = (N + 3) / 4;
    int mfma_blocks = (N + 31) / 32;

    // ---- layer 0 ----
    k_gather<<<gather_blocks, 256, 0, stream>>>(rowptr, col, x, agg, N);
    k_sage_mfma<8><<<mfma_blocks, 256, 0, stream>>>(x, agg, pk0, bl0, h, N, HDIM);
    hipMemsetAsync(stats, 0, 2 * HDIM * sizeof(float), stream);
    k_bnstats<<<256, 256, 0, stream>>>(h, stats, N);
    k_bnapply<<<(int)(((size_t)N * 32 + 255) / 256), 256, 0, stream>>>(h, stats, g0, b0, N);

    // ---- layer 1 (in-place on h) ----
    k_gather<<<gather_blocks, 256, 0, stream>>>(rowptr, col, h, agg, N);
    k_sage_mfma<8><<<mfma_blocks, 256, 0, stream>>>(h, agg, pk1, bl1, h, N, HDIM);
    hipMemsetAsync(stats, 0, 2 * HDIM * sizeof(float), stream);
    k_bnstats<<<256, 256, 0, stream>>>(h, stats, N);
    k_bnapply<<<(int)(((size_t)N * 32 + 255) / 256), 256, 0, stream>>>(h, stats, g1, b1, N);

    // ---- output layer ----
    k_gather<<<gather_blocks, 256, 0, stream>>>(rowptr, col, h, agg, N);
    k_sage_mfma<3><<<mfma_blocks, 256, 0, stream>>>(h, agg, pko, blo, out, N, C);
    k_logsoftmax<<<(N * 64 + 255) / 256, 256, 0, stream>>>(out, N, C);
}